// Round 6
// baseline (17614.763 us; speedup 1.0000x reference)
//
#include <hip/hip_runtime.h>
#include <hip/hip_bf16.h>
#include <math.h>

#define T_STEPS 512
#define BATCH   64
#define HID     1024
#define G3      3072
#define BH      (BATCH * HID)

typedef __attribute__((ext_vector_type(8))) short          bf16x8;
typedef __attribute__((ext_vector_type(8))) unsigned short u16x8;
typedef __attribute__((ext_vector_type(4))) float          f32x4;
typedef unsigned long long u64;

__device__ inline unsigned short f2bf(float f) {
    __hip_bfloat16 h = __float2bfloat16(f);
    return *reinterpret_cast<unsigned short*>(&h);
}

__device__ inline float fast_sigmoid(float x) {
    return __builtin_amdgcn_rcpf(1.f + __expf(-x));
}
__device__ inline float fast_tanh(float x) {
    float e = __expf(-2.f * fabsf(x));
    float t = (1.f - e) * __builtin_amdgcn_rcpf(1.f + e);
    return copysignf(t, x);
}

// unpack 8 bf16 (cols c0..c7) from 3 stamped words {h0,h1,h2,stamp}
__device__ inline bf16x8 unpack3(u64 a, u64 b, u64 c) {
    union { unsigned int r[4]; bf16x8 v; } u;
    u.r[0] = (unsigned int)a;                                       // c0|c1
    u.r[1] = (unsigned int)((a >> 32) & 0xFFFFull)
           | ((unsigned int)(b & 0xFFFFull) << 16);                 // c2|c3
    u.r[2] = (unsigned int)(b >> 16);                               // c4|c5
    u.r[3] = (unsigned int)c;                                       // c6|c7
    return u.v;
}

// blob word index: slot s, batch-group bg, col-tile jt, word w(0..7), row(0..15)
__device__ __host__ inline size_t g_blob(int s, int bg, int jt, int w, int row) {
    return ((((size_t)s * 4 + bg) * 64 + jt) * 128) + (size_t)w * 16 + row;
}

// ---------------------------------------------------------------------------
__global__ void cvt_f32_bf16(const float* __restrict__ src,
                             unsigned short* __restrict__ dst, int n)
{
    int i = (blockIdx.x * blockDim.x + threadIdx.x) * 4;
    if (i + 3 < n) {
        float4 v = *(const float4*)(src + i);
        ushort4 o;
        o.x = f2bf(v.x); o.y = f2bf(v.y); o.z = f2bf(v.z); o.w = f2bf(v.w);
        *(ushort4*)(dst + i) = o;
    }
}

// ---------------------------------------------------------------------------
// pack initial h (f32) into stamped blobs, version 0 of `layer`
// ---------------------------------------------------------------------------
__global__ void init_pack(const float* __restrict__ h0L,
                          u64* __restrict__ blobs, int layer)
{
    int idx = blockIdx.x * 256 + threadIdx.x;     // 96*256 = 24576 used words
    int bg  = idx / 6144;
    int r1  = idx % 6144;
    int jt  = r1 / 96;
    int r2  = r1 % 96;
    int w6  = r2 / 16;
    int row = r2 % 16;
    int w   = w6 + (w6 >= 3 ? 1 : 0);
    int cb  = (w6 < 3) ? w6 * 3 : 8 + (w6 - 3) * 3;
    int nv  = (w6 == 2 || w6 == 5) ? 2 : 3;
    int b   = bg * 16 + row;
    int c0  = jt * 16 + cb;
    unsigned int stamp = (unsigned int)(layer * 520 + 1);
    u64 v0 = f2bf(h0L[(size_t)b * HID + c0]);
    u64 v1 = f2bf(h0L[(size_t)b * HID + c0 + 1]);
    u64 v2 = (nv == 3) ? (u64)f2bf(h0L[(size_t)b * HID + c0 + 2]) : 0ull;
    u64 word = v0 | (v1 << 16) | (v2 << 32) | ((u64)(stamp & 0xFFFF) << 48);
    blobs[g_blob(stamp & 1, bg, jt, w, row)] = word;
}

// ---------------------------------------------------------------------------
// gx GEMM: C[M][3072] = A[M][1024](f32, cvt on the fly) @ Wbf[3072][1024]^T + b
// ---------------------------------------------------------------------------
__global__ __launch_bounds__(256) void gemm_gx_bf16(
    const float* __restrict__ A, const unsigned short* __restrict__ Wbf,
    const float* __restrict__ bias, float* __restrict__ C, int M)
{
    __shared__ unsigned short As[128][72];
    __shared__ unsigned short Bs[128][72];
    const int tid = threadIdx.x;
    const int l  = tid & 63;
    const int w  = tid >> 6;
    const int wm = w >> 1, wn = w & 1;
    const int m0 = blockIdx.y * 128, n0 = blockIdx.x * 128;
    const int lr = l & 15, lk = (l >> 4) * 8;

    f32x4 acc[4][4] = {};

    const int arow = tid >> 4, acol = (tid & 15) * 4;
    const int brow = tid >> 3, bcol = (tid & 7) * 8;

    for (int k0 = 0; k0 < 1024; k0 += 64) {
        float4 av[8];
        #pragma unroll
        for (int r = 0; r < 8; ++r)
            av[r] = *(const float4*)(A + (size_t)(m0 + r * 16 + arow) * 1024 + k0 + acol);
        u16x8 bv[4];
        #pragma unroll
        for (int r = 0; r < 4; ++r)
            bv[r] = *(const u16x8*)(Wbf + (size_t)(n0 + r * 32 + brow) * 1024 + k0 + bcol);

        __syncthreads();
        #pragma unroll
        for (int r = 0; r < 8; ++r) {
            ushort4 o;
            o.x = f2bf(av[r].x); o.y = f2bf(av[r].y);
            o.z = f2bf(av[r].z); o.w = f2bf(av[r].w);
            *(ushort4*)&As[r * 16 + arow][acol] = o;
        }
        #pragma unroll
        for (int r = 0; r < 4; ++r)
            *(u16x8*)&Bs[r * 32 + brow][bcol] = bv[r];
        __syncthreads();

        #pragma unroll
        for (int kk = 0; kk < 2; ++kk) {
            bf16x8 af[4], bfr[4];
            #pragma unroll
            for (int i = 0; i < 4; ++i)
                af[i] = *(const bf16x8*)&As[wm * 64 + i * 16 + lr][kk * 32 + lk];
            #pragma unroll
            for (int j = 0; j < 4; ++j)
                bfr[j] = *(const bf16x8*)&Bs[wn * 64 + j * 16 + lr][kk * 32 + lk];
            #pragma unroll
            for (int i = 0; i < 4; ++i)
                #pragma unroll
                for (int j = 0; j < 4; ++j)
                    acc[i][j] = __builtin_amdgcn_mfma_f32_16x16x32_bf16(
                        af[i], bfr[j], acc[i][j], 0, 0, 0);
        }
    }

    #pragma unroll
    for (int j = 0; j < 4; ++j) {
        const int col = n0 + wn * 64 + j * 16 + lr;
        const float bv = bias[col];
        #pragma unroll
        for (int i = 0; i < 4; ++i) {
            const int rb = m0 + wm * 64 + i * 16 + (l >> 4) * 4;
            #pragma unroll
            for (int r = 0; r < 4; ++r)
                C[(size_t)(rb + r) * G3 + col] = acc[i][j][r] + bv;
        }
    }
}

// ---------------------------------------------------------------------------
// Persistent recurrence, stamp-in-data protocol (single LLC round trip/step).
// 64 blocks x 256 thr. block = (ct = bid>>2 col-tile of 64, bg = bid&3);
// wave wid owns cols jt_self = ct*4+wid (16 cols), all 16 rows of bg, FULL K.
// Per step: all 256 threads poll+stage the bg's packed h (8192 u64) into LDS,
// then each wave runs 96 MFMAs (A from LDS-unpack, B = W_hh from L2), gates
// in-register (no reduce), packs its 16x16 h tile into stamped u64 blobs and
// fire-and-forget agent-stores them. Consumers spin on exact stamp equality.
// ---------------------------------------------------------------------------
__global__ __launch_bounds__(256, 1) void gru_persist(
    const float* __restrict__ gx,            // [tc][64][3072] chunk-local
    const float* __restrict__ hprev0,        // [64][1024] f32 h before step t0
    const unsigned short* __restrict__ whh,  // [3072][1024] bf16
    const float* __restrict__ bhh,           // [3072]
    float* __restrict__ y_all,               // [512][64][1024]
    u64* __restrict__ blobs,                 // [2][4][64][128] stamped words
    int layer, int t0, int tc)
{
    __shared__ u64 stage[64 * 129];            // [jt]*129 + w*16 + row (66 KB)
    __shared__ unsigned short tile[4][16][16]; // per-wave pack tile

    const int tid = threadIdx.x;
    const int bid = blockIdx.x;
    const int bg  = bid & 3;
    const int ct  = bid >> 2;
    const int l   = tid & 63;
    const int wid = tid >> 6;
    const int lr  = l & 15;
    const int lgrp = l >> 4;                  // 0..3
    const int jt_self = ct * 4 + wid;

    // ---- staging assignment: thread covers 32 consecutive words (2 w-blocks)
    const int jt_t = tid >> 2;
    const int w0   = (tid & 3) * 2;
    const int lbase = jt_t * 129 + w0 * 16;

    // ---- compute coords: this thread owns col j, rows b0..b0+3 (reg r)
    const int j  = jt_self * 16 + lr;
    const int b0 = bg * 16 + 4 * lgrp;
    const float bhr = bhh[j], bhz = bhh[HID + j], bhn = bhh[2 * HID + j];
    const size_t wofs_r = ((size_t)(0 * HID + j)) << 10;
    const size_t wofs_z = ((size_t)(1 * HID + j)) << 10;
    const size_t wofs_n = ((size_t)(2 * HID + j)) << 10;

    float hreg[4];
    #pragma unroll
    for (int r = 0; r < 4; ++r)
        hreg[r] = hprev0[(size_t)(b0 + r) * HID + j];

    // pack-store coords (lanes 0..47 of each wave)
    const int pw6a = lgrp;            // pass 0 word-group (valid when l<48)

    for (int ts = 0; ts < tc; ++ts) {
        const int t = t0 + ts;
        const unsigned int stamp_c = (unsigned int)(layer * 520 + t + 1);
        const unsigned int stamp_p = stamp_c + 1;
        const int slot_c = stamp_c & 1;
        const int slot_p = stamp_p & 1;
        const float* gx_t = gx + (size_t)ts * BATCH * G3;

        // prefetch gate inputs (independent of h) — hidden under poll+MFMA
        float gxv[3][4];
        #pragma unroll
        for (int g = 0; g < 3; ++g)
            #pragma unroll
            for (int r = 0; r < 4; ++r)
                gxv[g][r] = gx_t[(size_t)(b0 + r) * G3 + g * HID + j];

        // ---- poll + stage: 32 words, retry until all valid stamps match
        {
            const u64* gsrc = blobs + g_blob(slot_c, bg, jt_t, w0, 0);
            const unsigned short exp = (unsigned short)stamp_c;
            for (;;) {
                u64 v[32];
                #pragma unroll
                for (int i = 0; i < 32; ++i)
                    v[i] = __hip_atomic_load(gsrc + i, __ATOMIC_RELAXED,
                                             __HIP_MEMORY_SCOPE_AGENT);
                bool ok = true;
                #pragma unroll
                for (int i = 0; i < 32; ++i) {
                    const int w = w0 + (i >> 4);
                    const bool valid = (w != 3) && (w != 7);
                    ok &= (!valid) || ((unsigned short)(v[i] >> 48) == exp);
                }
                if (ok) {
                    #pragma unroll
                    for (int i = 0; i < 32; ++i)
                        stage[lbase + i] = v[i];
                    break;
                }
                __builtin_amdgcn_s_sleep(1);
            }
        }
        __syncthreads();   // stage complete for all 64 jt

        // ---- MFMA: full K per wave, 3 gates
        f32x4 ar = {0.f, 0.f, 0.f, 0.f};
        f32x4 az = {0.f, 0.f, 0.f, 0.f};
        f32x4 an = {0.f, 0.f, 0.f, 0.f};
        #pragma unroll 4
        for (int kt = 0; kt < 32; ++kt) {
            const int jtk = kt * 2 + (lgrp >> 1);
            const int lb  = jtk * 129 + ((lgrp & 1) * 4) * 16 + lr;
            u64 wa = stage[lb];
            u64 wb = stage[lb + 16];
            u64 wc = stage[lb + 32];
            bf16x8 A = unpack3(wa, wb, wc);
            const unsigned short* wk = whh + (size_t)kt * 32 + lgrp * 8;
            bf16x8 Br = *(const bf16x8*)(wk + wofs_r);
            bf16x8 Bz = *(const bf16x8*)(wk + wofs_z);
            bf16x8 Bn = *(const bf16x8*)(wk + wofs_n);
            ar = __builtin_amdgcn_mfma_f32_16x16x32_bf16(A, Br, ar, 0, 0, 0);
            az = __builtin_amdgcn_mfma_f32_16x16x32_bf16(A, Bz, az, 0, 0, 0);
            an = __builtin_amdgcn_mfma_f32_16x16x32_bf16(A, Bn, an, 0, 0, 0);
        }

        // ---- gates, y store, pack tile
        #pragma unroll
        for (int r = 0; r < 4; ++r) {
            const float rg = fast_sigmoid(gxv[0][r] + ar[r] + bhr);
            const float zg = fast_sigmoid(gxv[1][r] + az[r] + bhz);
            const float ng = fast_tanh(gxv[2][r] + rg * (an[r] + bhn));
            const float hn = ng + zg * (hreg[r] - ng);
            hreg[r] = hn;
            y_all[(size_t)t * BH + (size_t)(b0 + r) * HID + j] = hn;
            tile[wid][4 * lgrp + r][lr] = f2bf(hn);
        }

        // ---- pack + fire agent stores (no drain, stamp travels with data)
        if (l < 48) {
            const unsigned short st = (unsigned short)stamp_p;
            #pragma unroll
            for (int p = 0; p < 2; ++p) {
                const int w6 = p * 3 + pw6a;
                const int w  = w6 + (w6 >= 3 ? 1 : 0);
                const int cb = (w6 < 3) ? w6 * 3 : 8 + (w6 - 3) * 3;
                const int row = lr;
                u64 t0v = tile[wid][row][cb];
                u64 t1v = tile[wid][row][cb + 1];
                u64 t2v = (w6 == 2 || w6 == 5) ? 0ull
                          : (u64)tile[wid][row][cb + 2];
                u64 word = t0v | (t1v << 16) | (t2v << 32) | ((u64)st << 48);
                __hip_atomic_store(blobs + g_blob(slot_p, bg, jt_self, w, row),
                                   word, __ATOMIC_RELAXED,
                                   __HIP_MEMORY_SCOPE_AGENT);
            }
        }

        __syncthreads();   // all waves done reading `stage` before next overwrite
    }
}

__global__ void copy_f32(const float* __restrict__ src, float* __restrict__ dst, int n)
{
    int i = blockIdx.x * blockDim.x + threadIdx.x;
    if (i < n) dst[i] = src[i];
}

// ---------------------------------------------------------------------------
extern "C" void kernel_launch(void* const* d_in, const int* in_sizes, int n_in,
                              void* d_out, int out_size, void* d_ws, size_t ws_size,
                              hipStream_t stream)
{
    const float* x    = (const float*)d_in[0];
    const float* h0   = (const float*)d_in[1];
    const float* wih[2] = {(const float*)d_in[2], (const float*)d_in[6]};
    const float* whh[2] = {(const float*)d_in[3], (const float*)d_in[7]};
    const float* bih[2] = {(const float*)d_in[4], (const float*)d_in[8]};
    const float* bhh[2] = {(const float*)d_in[5], (const float*)d_in[9]};

    float* out = (float*)d_out;
    float* y   = out;                                  // [512][64][1024]
    float* hn  = out + (size_t)T_STEPS * BH;           // [2][64][1024]

    const size_t WSZ = (size_t)G3 * HID;               // 3145728 elems
    unsigned short* wsu = (unsigned short*)d_ws;
    unsigned short* whh_bf[2] = {wsu, wsu + WSZ};
    unsigned short* wih_bf[2] = {wsu + 2 * WSZ, wsu + 3 * WSZ};
    u64* blobs = (u64*)(wsu + 4 * WSZ);
    const size_t BLOB_N = 2ull * 4 * 64 * 128;         // 65536 u64 = 512 KB
    float* gx = (float*)(blobs + BLOB_N);
    const size_t fixed_bytes = 4 * WSZ * 2 + BLOB_N * 8;
    const size_t gx_bytes = ws_size > fixed_bytes ? ws_size - fixed_bytes : 0;

    int TC = 512;
    while (TC > 2 && (size_t)TC * BATCH * G3 * 4 > gx_bytes) TC >>= 1;

    hipMemsetAsync(blobs, 0, BLOB_N * 8, stream);      // stale stamps can't match

    for (int layer = 0; layer < 2; ++layer) {
        cvt_f32_bf16<<<(int)(WSZ / 1024), 256, 0, stream>>>(whh[layer], whh_bf[layer], (int)WSZ);
        cvt_f32_bf16<<<(int)(WSZ / 1024), 256, 0, stream>>>(wih[layer], wih_bf[layer], (int)WSZ);
    }

    for (int layer = 0; layer < 2; ++layer) {
        const float* A_all = (layer == 0) ? x : y;
        const float* hinit = h0 + (size_t)layer * BH;

        init_pack<<<96, 256, 0, stream>>>(hinit, blobs, layer);

        for (int c0 = 0; c0 < T_STEPS; c0 += TC) {
            dim3 ggrid(G3 / 128, TC * BATCH / 128);
            gemm_gx_bf16<<<ggrid, 256, 0, stream>>>(
                A_all + (size_t)c0 * BH, wih_bf[layer], bih[layer],
                gx, TC * BATCH);

            const float* gxp = gx;
            const float* hprev0 = (c0 == 0) ? hinit : (y + (size_t)(c0 - 1) * BH);
            const unsigned short* whhp = whh_bf[layer];
            const float* bhhp = bhh[layer];
            float* yp = y;
            u64* blp = blobs;
            int lv = layer, t0v = c0, tcv = TC;
            void* kargs[] = {(void*)&gxp, (void*)&hprev0, (void*)&whhp,
                             (void*)&bhhp, (void*)&yp, (void*)&blp,
                             (void*)&lv, (void*)&t0v, (void*)&tcv};
            hipLaunchCooperativeKernel((const void*)gru_persist,
                                       dim3(64), dim3(256), kargs, 0, stream);
        }
        copy_f32<<<(BH + 255) / 256, 256, 0, stream>>>(
            y + (size_t)(T_STEPS - 1) * BH, hn + (size_t)layer * BH, BH);
    }
}

// Round 7
// 8861.604 us; speedup vs baseline: 1.9878x; 1.9878x over previous
//
#include <hip/hip_runtime.h>
#include <hip/hip_bf16.h>
#include <math.h>

#define T_STEPS 512
#define BATCH   64
#define HID     1024
#define G3      3072
#define BH      (BATCH * HID)

typedef __attribute__((ext_vector_type(8))) short          bf16x8;
typedef __attribute__((ext_vector_type(8))) unsigned short u16x8;
typedef __attribute__((ext_vector_type(4))) float          f32x4;
typedef unsigned long long u64;

__device__ inline unsigned short f2bf(float f) {
    __hip_bfloat16 h = __float2bfloat16(f);
    return *reinterpret_cast<unsigned short*>(&h);
}

__device__ inline float fast_sigmoid(float x) {
    return __builtin_amdgcn_rcpf(1.f + __expf(-x));
}
__device__ inline float fast_tanh(float x) {
    float e = __expf(-2.f * fabsf(x));
    float t = (1.f - e) * __builtin_amdgcn_rcpf(1.f + e);
    return copysignf(t, x);
}

// ---------------------------------------------------------------------------
__global__ void cvt_f32_bf16(const float* __restrict__ src,
                             unsigned short* __restrict__ dst, int n)
{
    int i = (blockIdx.x * blockDim.x + threadIdx.x) * 4;
    if (i + 3 < n) {
        float4 v = *(const float4*)(src + i);
        ushort4 o;
        o.x = f2bf(v.x); o.y = f2bf(v.y); o.z = f2bf(v.z); o.w = f2bf(v.w);
        *(ushort4*)(dst + i) = o;
    }
}

// ---------------------------------------------------------------------------
// pack initial h (f32) into stamped words: {bf16 even-col | bf16 odd-col |
// stamp}<<32. Word index: slot*32768 + b*512 + colpair.
// ---------------------------------------------------------------------------
__global__ void init_pack(const float* __restrict__ h0L,
                          u64* __restrict__ hpk, int layer)
{
    int idx = blockIdx.x * 256 + threadIdx.x;   // 64*512 = 32768 words
    if (idx >= 64 * 512) return;
    int b = idx >> 9, cp = idx & 511;
    unsigned int stamp = (unsigned int)(layer * 520 + 1);
    u64 lo = f2bf(h0L[(size_t)b * HID + 2 * cp]);
    u64 hi = f2bf(h0L[(size_t)b * HID + 2 * cp + 1]);
    u64 word = lo | (hi << 16) | ((u64)(stamp & 0xFFFF) << 32);
    hpk[(size_t)(stamp & 1) * 32768 + idx] = word;
}

// ---------------------------------------------------------------------------
// gx GEMM: C[M][3072] = A[M][1024](f32, cvt on the fly) @ Wbf[3072][1024]^T + b
// ---------------------------------------------------------------------------
__global__ __launch_bounds__(256) void gemm_gx_bf16(
    const float* __restrict__ A, const unsigned short* __restrict__ Wbf,
    const float* __restrict__ bias, float* __restrict__ C, int M)
{
    __shared__ unsigned short As[128][72];
    __shared__ unsigned short Bs[128][72];
    const int tid = threadIdx.x;
    const int l  = tid & 63;
    const int w  = tid >> 6;
    const int wm = w >> 1, wn = w & 1;
    const int m0 = blockIdx.y * 128, n0 = blockIdx.x * 128;
    const int lr = l & 15, lk = (l >> 4) * 8;

    f32x4 acc[4][4] = {};

    const int arow = tid >> 4, acol = (tid & 15) * 4;
    const int brow = tid >> 3, bcol = (tid & 7) * 8;

    for (int k0 = 0; k0 < 1024; k0 += 64) {
        float4 av[8];
        #pragma unroll
        for (int r = 0; r < 8; ++r)
            av[r] = *(const float4*)(A + (size_t)(m0 + r * 16 + arow) * 1024 + k0 + acol);
        u16x8 bv[4];
        #pragma unroll
        for (int r = 0; r < 4; ++r)
            bv[r] = *(const u16x8*)(Wbf + (size_t)(n0 + r * 32 + brow) * 1024 + k0 + bcol);

        __syncthreads();
        #pragma unroll
        for (int r = 0; r < 8; ++r) {
            ushort4 o;
            o.x = f2bf(av[r].x); o.y = f2bf(av[r].y);
            o.z = f2bf(av[r].z); o.w = f2bf(av[r].w);
            *(ushort4*)&As[r * 16 + arow][acol] = o;
        }
        #pragma unroll
        for (int r = 0; r < 4; ++r)
            *(u16x8*)&Bs[r * 32 + brow][bcol] = bv[r];
        __syncthreads();

        #pragma unroll
        for (int kk = 0; kk < 2; ++kk) {
            bf16x8 af[4], bfr[4];
            #pragma unroll
            for (int i = 0; i < 4; ++i)
                af[i] = *(const bf16x8*)&As[wm * 64 + i * 16 + lr][kk * 32 + lk];
            #pragma unroll
            for (int j = 0; j < 4; ++j)
                bfr[j] = *(const bf16x8*)&Bs[wn * 64 + j * 16 + lr][kk * 32 + lk];
            #pragma unroll
            for (int i = 0; i < 4; ++i)
                #pragma unroll
                for (int j = 0; j < 4; ++j)
                    acc[i][j] = __builtin_amdgcn_mfma_f32_16x16x32_bf16(
                        af[i], bfr[j], acc[i][j], 0, 0, 0);
        }
    }

    #pragma unroll
    for (int j = 0; j < 4; ++j) {
        const int col = n0 + wn * 64 + j * 16 + lr;
        const float bv = bias[col];
        #pragma unroll
        for (int i = 0; i < 4; ++i) {
            const int rb = m0 + wm * 64 + i * 16 + (l >> 4) * 4;
            #pragma unroll
            for (int r = 0; r < 4; ++r)
                C[(size_t)(rb + r) * G3 + col] = acc[i][j][r] + bv;
        }
    }
}

// ---------------------------------------------------------------------------
// Persistent recurrence, stamp-in-data protocol on the 256-block structure.
// block = (jt = bid&63, bg = bid>>6); 4 waves split K (256 each). Per step,
// each wave polls its disjoint k-slice of bg's packed h (32 u64/lane, stamp
// embedded per word) straight into registers — no LDS staging, no flags, no
// producer drain. A-frag = 4x lo32 extracts. Cross-wave reduce in 13-padded
// LDS; 256 threads finalize; producers pack+fire h stores (stamp in word).
// ---------------------------------------------------------------------------
__global__ __launch_bounds__(256, 1) void gru_persist(
    const float* __restrict__ gx,            // [tc][64][3072] chunk-local
    const float* __restrict__ hprev0,        // [64][1024] f32 h before step t0
    const unsigned short* __restrict__ whh,  // [3072][1024] bf16
    const float* __restrict__ bhh,           // [3072]
    float* __restrict__ y_all,               // [512][64][1024]
    u64* __restrict__ hpk,                   // [2][64][512] stamped words
    int layer, int t0, int tc)
{
    __shared__ float red[4][64][13];

    const int tid = threadIdx.x;
    const int bid = blockIdx.x;
    const int jt = bid & 63;
    const int bg = bid >> 6;
    const int l   = tid & 63;
    const int ks  = tid >> 6;          // wave = k-slice (256 k)
    const int lr  = l & 15;
    const int lgrp = l >> 4;           // 0..3

    // consumer poll base: row = bg*16+lr, col-pairs ks*128 + kc*16 + lgrp*4
    const size_t prow = (size_t)(bg * 16 + lr) * 512 + ks * 128 + lgrp * 4;

    // B base: col j = jt*16+lr, k-offset = ks*256 + lgrp*8
    const unsigned short* wr = whh + ((size_t)(jt * 16 + lr) << 10) + ks * 256 + lgrp * 8;
    const unsigned short* wz = wr + (size_t)HID * HID;
    const unsigned short* wn = wz + (size_t)HID * HID;

    // finalize coords: thread (fl, q) -> (col j, batch b)
    const int q  = tid >> 6;
    const int fl = tid & 63;
    const int j  = jt * 16 + (fl & 15);
    const int b  = bg * 16 + 4 * (fl >> 4) + q;
    const float bhr = bhh[j], bhz = bhh[HID + j], bhn = bhh[2 * HID + j];
    float hreg = hprev0[(size_t)b * HID + j];

    for (int ts = 0; ts < tc; ++ts) {
        const int t = t0 + ts;
        const unsigned int stamp_c = (unsigned int)(layer * 520 + t + 1);
        const unsigned int stamp_p = stamp_c + 1;
        const size_t base_c = (size_t)(stamp_c & 1) * 32768 + prow;
        const size_t base_p = (size_t)(stamp_p & 1) * 32768;
        const float* gx_t = gx + (size_t)ts * BATCH * G3;

        // gate inputs (independent of h): in flight during the poll
        const float gxr = gx_t[(size_t)b * G3 + j];
        const float gxz = gx_t[(size_t)b * G3 + HID + j];
        const float gxn = gx_t[(size_t)b * G3 + 2 * HID + j];

        // ---- poll this wave's k-slice until every word carries stamp_c
        u64 v[32];
        {
            const unsigned int exp = stamp_c & 0xFFFFu;
            for (;;) {
                #pragma unroll
                for (int kc = 0; kc < 8; ++kc)
                    #pragma unroll
                    for (int m = 0; m < 4; ++m)
                        v[kc * 4 + m] = __hip_atomic_load(
                            hpk + base_c + kc * 16 + m,
                            __ATOMIC_RELAXED, __HIP_MEMORY_SCOPE_AGENT);
                bool ok = true;
                #pragma unroll
                for (int i = 0; i < 32; ++i)
                    ok &= (((unsigned int)(v[i] >> 32) & 0xFFFFu) == exp);
                if (__ballot(!ok) == 0ull) break;
                __builtin_amdgcn_s_sleep(1);
            }
        }

        // ---- MFMA over this wave's 256-k slice (A = lo32 extracts)
        f32x4 ar = {0.f, 0.f, 0.f, 0.f};
        f32x4 az = {0.f, 0.f, 0.f, 0.f};
        f32x4 an = {0.f, 0.f, 0.f, 0.f};
        #pragma unroll
        for (int kc = 0; kc < 8; ++kc) {
            union { unsigned int r[4]; bf16x8 v8; } ua;
            ua.r[0] = (unsigned int)v[kc * 4 + 0];
            ua.r[1] = (unsigned int)v[kc * 4 + 1];
            ua.r[2] = (unsigned int)v[kc * 4 + 2];
            ua.r[3] = (unsigned int)v[kc * 4 + 3];
            bf16x8 Br = *(const bf16x8*)(wr + kc * 32);
            bf16x8 Bz = *(const bf16x8*)(wz + kc * 32);
            bf16x8 Bn = *(const bf16x8*)(wn + kc * 32);
            ar = __builtin_amdgcn_mfma_f32_16x16x32_bf16(ua.v8, Br, ar, 0, 0, 0);
            az = __builtin_amdgcn_mfma_f32_16x16x32_bf16(ua.v8, Bz, az, 0, 0, 0);
            an = __builtin_amdgcn_mfma_f32_16x16x32_bf16(ua.v8, Bn, an, 0, 0, 0);
        }
        #pragma unroll
        for (int i = 0; i < 4; ++i) {
            red[ks][l][i]     = ar[i];
            red[ks][l][4 + i] = az[i];
            red[ks][l][8 + i] = an[i];
        }
        __syncthreads();

        float sr = 0.f, sz = 0.f, sn = 0.f;
        #pragma unroll
        for (int s = 0; s < 4; ++s) {
            sr += red[s][fl][q];
            sz += red[s][fl][4 + q];
            sn += red[s][fl][8 + q];
        }
        const float rg = fast_sigmoid(gxr + sr + bhr);
        const float zg = fast_sigmoid(gxz + sz + bhz);
        const float ng = fast_tanh(gxn + rg * (sn + bhn));
        hreg = ng + zg * (hreg - ng);

        // ---- pack + fire h store (stamp travels with data; no drain)
        unsigned int myu = (unsigned int)f2bf(hreg);
        unsigned int pu  = __shfl_xor(myu, 1);
        if (!(fl & 1)) {
            u64 word = (u64)(myu | (pu << 16))
                     | ((u64)(stamp_p & 0xFFFF) << 32);
            __hip_atomic_store(hpk + base_p + (size_t)b * 512 + (j >> 1), word,
                               __ATOMIC_RELAXED, __HIP_MEMORY_SCOPE_AGENT);
        }

        // off the critical path: y store
        y_all[(size_t)t * BH + (size_t)b * HID + j] = hreg;

        __syncthreads();   // red consumed by all waves before next overwrite
    }
}

__global__ void copy_f32(const float* __restrict__ src, float* __restrict__ dst, int n)
{
    int i = blockIdx.x * blockDim.x + threadIdx.x;
    if (i < n) dst[i] = src[i];
}

// ---------------------------------------------------------------------------
extern "C" void kernel_launch(void* const* d_in, const int* in_sizes, int n_in,
                              void* d_out, int out_size, void* d_ws, size_t ws_size,
                              hipStream_t stream)
{
    const float* x    = (const float*)d_in[0];
    const float* h0   = (const float*)d_in[1];
    const float* wih[2] = {(const float*)d_in[2], (const float*)d_in[6]};
    const float* whh[2] = {(const float*)d_in[3], (const float*)d_in[7]};
    const float* bih[2] = {(const float*)d_in[4], (const float*)d_in[8]};
    const float* bhh[2] = {(const float*)d_in[5], (const float*)d_in[9]};

    float* out = (float*)d_out;
    float* y   = out;                                  // [512][64][1024]
    float* hn  = out + (size_t)T_STEPS * BH;           // [2][64][1024]

    const size_t WSZ = (size_t)G3 * HID;               // 3145728 elems
    unsigned short* wsu = (unsigned short*)d_ws;
    unsigned short* whh_bf[2] = {wsu, wsu + WSZ};
    unsigned short* wih_bf[2] = {wsu + 2 * WSZ, wsu + 3 * WSZ};
    u64* hpk = (u64*)(wsu + 4 * WSZ);
    const size_t HPK_N = 2ull * 64 * 512;              // 65536 u64 = 512 KB
    float* gx = (float*)(hpk + HPK_N);
    const size_t fixed_bytes = 4 * WSZ * 2 + HPK_N * 8;
    const size_t gx_bytes = ws_size > fixed_bytes ? ws_size - fixed_bytes : 0;

    int TC = 512;
    while (TC > 2 && (size_t)TC * BATCH * G3 * 4 > gx_bytes) TC >>= 1;

    hipMemsetAsync(hpk, 0, HPK_N * 8, stream);         // stale stamps can't match

    for (int layer = 0; layer < 2; ++layer) {
        cvt_f32_bf16<<<(int)(WSZ / 1024), 256, 0, stream>>>(whh[layer], whh_bf[layer], (int)WSZ);
        cvt_f32_bf16<<<(int)(WSZ / 1024), 256, 0, stream>>>(wih[layer], wih_bf[layer], (int)WSZ);
    }

    for (int layer = 0; layer < 2; ++layer) {
        const float* A_all = (layer == 0) ? x : y;
        const float* hinit = h0 + (size_t)layer * BH;

        init_pack<<<128, 256, 0, stream>>>(hinit, hpk, layer);

        for (int c0 = 0; c0 < T_STEPS; c0 += TC) {
            dim3 ggrid(G3 / 128, TC * BATCH / 128);
            gemm_gx_bf16<<<ggrid, 256, 0, stream>>>(
                A_all + (size_t)c0 * BH, wih_bf[layer], bih[layer],
                gx, TC * BATCH);

            const float* gxp = gx;
            const float* hprev0 = (c0 == 0) ? hinit : (y + (size_t)(c0 - 1) * BH);
            const unsigned short* whhp = whh_bf[layer];
            const float* bhhp = bhh[layer];
            float* yp = y;
            u64* hp = hpk;
            int lv = layer, t0v = c0, tcv = TC;
            void* kargs[] = {(void*)&gxp, (void*)&hprev0, (void*)&whhp,
                             (void*)&bhhp, (void*)&yp, (void*)&hp,
                             (void*)&lv, (void*)&t0v, (void*)&tcv};
            hipLaunchCooperativeKernel((const void*)gru_persist,
                                       dim3(256), dim3(256), kargs, 0, stream);
        }
        copy_f32<<<(BH + 255) / 256, 256, 0, stream>>>(
            y + (size_t)(T_STEPS - 1) * BH, hn + (size_t)layer * BH, BH);
    }
}

// Round 8
// 7546.016 us; speedup vs baseline: 2.3343x; 1.1743x over previous
//
#include <hip/hip_runtime.h>
#include <hip/hip_bf16.h>
#include <math.h>

#define T_STEPS 512
#define BATCH   64
#define HID     1024
#define G3      3072
#define BH      (BATCH * HID)

typedef __attribute__((ext_vector_type(8))) short          bf16x8;
typedef __attribute__((ext_vector_type(8))) unsigned short u16x8;
typedef __attribute__((ext_vector_type(4))) float          f32x4;
typedef unsigned long long u64;

__device__ inline unsigned short f2bf(float f) {
    __hip_bfloat16 h = __float2bfloat16(f);
    return *reinterpret_cast<unsigned short*>(&h);
}

// agent-scope (cross-XCD coherent) 16B load of bf16x8, bypassing stale L1/L2
__device__ inline bf16x8 load_h8(const unsigned short* p) {
    u64 lo = __hip_atomic_load((const u64*)p,       __ATOMIC_RELAXED, __HIP_MEMORY_SCOPE_AGENT);
    u64 hi = __hip_atomic_load((const u64*)(p + 4), __ATOMIC_RELAXED, __HIP_MEMORY_SCOPE_AGENT);
    union { u64 q[2]; bf16x8 v; } u;
    u.q[0] = lo; u.q[1] = hi;
    return u.v;
}

__device__ inline float fast_sigmoid(float x) {
    return __builtin_amdgcn_rcpf(1.f + __expf(-x));
}
__device__ inline float fast_tanh(float x) {
    float e = __expf(-2.f * fabsf(x));
    float t = (1.f - e) * __builtin_amdgcn_rcpf(1.f + e);
    return copysignf(t, x);
}

// barrier variants that do NOT drain vmcnt (compiler's __syncthreads does)
__device__ inline void bar_lgkm() {
    asm volatile("s_waitcnt lgkmcnt(0)" ::: "memory");
    __builtin_amdgcn_s_barrier();
    __builtin_amdgcn_sched_barrier(0);
}
__device__ inline void bar_only() {
    __builtin_amdgcn_s_barrier();
    __builtin_amdgcn_sched_barrier(0);
}

// ---------------------------------------------------------------------------
__global__ void cvt_f32_bf16(const float* __restrict__ src,
                             unsigned short* __restrict__ dst, int n)
{
    int i = (blockIdx.x * blockDim.x + threadIdx.x) * 4;
    if (i + 3 < n) {
        float4 v = *(const float4*)(src + i);
        ushort4 o;
        o.x = f2bf(v.x); o.y = f2bf(v.y); o.z = f2bf(v.z); o.w = f2bf(v.w);
        *(ushort4*)(dst + i) = o;
    }
}

// ---------------------------------------------------------------------------
// gx GEMM: C[M][3072] = A[M][1024](f32, cvt on the fly) @ Wbf[3072][1024]^T + b
// ---------------------------------------------------------------------------
__global__ __launch_bounds__(256) void gemm_gx_bf16(
    const float* __restrict__ A, const unsigned short* __restrict__ Wbf,
    const float* __restrict__ bias, float* __restrict__ C, int M)
{
    __shared__ unsigned short As[128][72];
    __shared__ unsigned short Bs[128][72];
    const int tid = threadIdx.x;
    const int l  = tid & 63;
    const int w  = tid >> 6;
    const int wm = w >> 1, wn = w & 1;
    const int m0 = blockIdx.y * 128, n0 = blockIdx.x * 128;
    const int lr = l & 15, lk = (l >> 4) * 8;

    f32x4 acc[4][4] = {};

    const int arow = tid >> 4, acol = (tid & 15) * 4;
    const int brow = tid >> 3, bcol = (tid & 7) * 8;

    for (int k0 = 0; k0 < 1024; k0 += 64) {
        float4 av[8];
        #pragma unroll
        for (int r = 0; r < 8; ++r)
            av[r] = *(const float4*)(A + (size_t)(m0 + r * 16 + arow) * 1024 + k0 + acol);
        u16x8 bv[4];
        #pragma unroll
        for (int r = 0; r < 4; ++r)
            bv[r] = *(const u16x8*)(Wbf + (size_t)(n0 + r * 32 + brow) * 1024 + k0 + bcol);

        __syncthreads();
        #pragma unroll
        for (int r = 0; r < 8; ++r) {
            ushort4 o;
            o.x = f2bf(av[r].x); o.y = f2bf(av[r].y);
            o.z = f2bf(av[r].z); o.w = f2bf(av[r].w);
            *(ushort4*)&As[r * 16 + arow][acol] = o;
        }
        #pragma unroll
        for (int r = 0; r < 4; ++r)
            *(u16x8*)&Bs[r * 32 + brow][bcol] = bv[r];
        __syncthreads();

        #pragma unroll
        for (int kk = 0; kk < 2; ++kk) {
            bf16x8 af[4], bfr[4];
            #pragma unroll
            for (int i = 0; i < 4; ++i)
                af[i] = *(const bf16x8*)&As[wm * 64 + i * 16 + lr][kk * 32 + lk];
            #pragma unroll
            for (int j = 0; j < 4; ++j)
                bfr[j] = *(const bf16x8*)&Bs[wn * 64 + j * 16 + lr][kk * 32 + lk];
            #pragma unroll
            for (int i = 0; i < 4; ++i)
                #pragma unroll
                for (int j = 0; j < 4; ++j)
                    acc[i][j] = __builtin_amdgcn_mfma_f32_16x16x32_bf16(
                        af[i], bfr[j], acc[i][j], 0, 0, 0);
        }
    }

    #pragma unroll
    for (int j = 0; j < 4; ++j) {
        const int col = n0 + wn * 64 + j * 16 + lr;
        const float bv = bias[col];
        #pragma unroll
        for (int i = 0; i < 4; ++i) {
            const int rb = m0 + wm * 64 + i * 16 + (l >> 4) * 4;
            #pragma unroll
            for (int r = 0; r < 4; ++r)
                C[(size_t)(rb + r) * G3 + col] = acc[i][j][r] + bv;
        }
    }
}

// ---------------------------------------------------------------------------
// Persistent recurrence (round-5 structure + LDS weights + vmcnt-free bars).
// 256 blocks x 256 thr, block = (jt = bid&63, bg = bid>>6); 4 waves split K.
// W_hh block slice (98 KB) staged ONCE into LDS; per step each wave reads its
// B-fragments via ds_read_b128 (2-way = free). Flag barrier: h pack-store ->
// per-wave vmcnt(0) -> s_barrier -> tid0 flag store -> y store + gx prefetch
// (complete under the spin) -> wave0 polls 64 flags -> s_barrier.
// ---------------------------------------------------------------------------
__global__ __launch_bounds__(256, 1) void gru_persist(
    const float* __restrict__ gx,            // [tc][64][3072] chunk-local
    unsigned short* __restrict__ hbf,        // 2 x [64][1024], parity = t&1
    const float* __restrict__ hprev0,        // [64][1024] f32 h before step t0
    const unsigned short* __restrict__ whh,  // [3072][1024] bf16
    const float* __restrict__ bhh,           // [3072]
    float* __restrict__ y_all,               // [512][64][1024]
    unsigned int* __restrict__ flags,        // [4][64] stamp words
    int step_base, int t0, int tc)
{
    __shared__ unsigned short wlds[3 * 4 * 8 * 4 * 16 * 8];  // 98304 B
    __shared__ float red[4][64][13];

    const int tid = threadIdx.x;
    const int bid = blockIdx.x;
    const int jt = bid & 63;
    const int bg = bid >> 6;
    const int l   = tid & 63;
    const int ks  = tid >> 6;          // wave = k-slice (256 k)
    const int lr  = l & 15;
    const int lgrp = l >> 4;           // 0..3

    // ---- stage W_hh slice into LDS once: vi = g*2048+ks*512+kc*64+lgrp*16+lr
    #pragma unroll
    for (int i = 0; i < 24; ++i) {
        int vi  = tid + i * 256;       // 0..6143
        int slr = vi & 15;
        int slg = (vi >> 4) & 3;
        int skc = (vi >> 6) & 7;
        int sks = (vi >> 9) & 3;
        int sg  = vi >> 11;
        u16x8 wv = *(const u16x8*)(whh
            + ((size_t)(sg * HID + jt * 16 + slr) << 10)
            + sks * 256 + skc * 32 + slg * 8);
        *(u16x8*)&wlds[(size_t)vi * 8] = wv;
    }

    const unsigned short* hpb = hbf + (size_t)(bg * 16 + lr) * HID + ks * 256 + lgrp * 8;
    const int wbase = (ks * 8) * 64 + lgrp * 16 + lr;   // vi for (g=0,ks,kc=0)

    // finalize coords: thread (fl, q) -> (col j, batch b)
    const int q  = tid >> 6;
    const int fl = tid & 63;
    const int j  = jt * 16 + (fl & 15);
    const int b  = bg * 16 + 4 * (fl >> 4) + q;
    const float bhr = bhh[j], bhz = bhh[HID + j], bhn = bhh[2 * HID + j];
    float hreg = hprev0[(size_t)b * HID + j];

    float gxr = gx[(size_t)b * G3 + j];
    float gxz = gx[(size_t)b * G3 + HID + j];
    float gxn = gx[(size_t)b * G3 + 2 * HID + j];

    bar_lgkm();   // weights staged

    for (int ts = 0; ts < tc; ++ts) {
        const int t = t0 + ts;
        const size_t coff = (size_t)(t & 1) * BH;
        const size_t noff = (size_t)((t + 1) & 1) * BH;
        const unsigned int stamp = (unsigned int)(step_base + ts + 1);

        // ---- MFMA: A from LLC (agent loads), B from LDS
        f32x4 ar = {0.f, 0.f, 0.f, 0.f};
        f32x4 az = {0.f, 0.f, 0.f, 0.f};
        f32x4 an = {0.f, 0.f, 0.f, 0.f};
        #pragma unroll
        for (int kc = 0; kc < 8; ++kc) {
            bf16x8 a  = load_h8(hpb + coff + kc * 32);
            bf16x8 Br = *(const bf16x8*)&wlds[(size_t)(wbase + kc * 64) * 8];
            bf16x8 Bz = *(const bf16x8*)&wlds[(size_t)(2048 + wbase + kc * 64) * 8];
            bf16x8 Bn = *(const bf16x8*)&wlds[(size_t)(4096 + wbase + kc * 64) * 8];
            ar = __builtin_amdgcn_mfma_f32_16x16x32_bf16(a, Br, ar, 0, 0, 0);
            az = __builtin_amdgcn_mfma_f32_16x16x32_bf16(a, Bz, az, 0, 0, 0);
            an = __builtin_amdgcn_mfma_f32_16x16x32_bf16(a, Bn, an, 0, 0, 0);
        }
        #pragma unroll
        for (int i = 0; i < 4; ++i) {
            red[ks][l][i]     = ar[i];
            red[ks][l][4 + i] = az[i];
            red[ks][l][8 + i] = an[i];
        }
        bar_lgkm();    // red visible; no vmcnt drain

        float sr = 0.f, sz = 0.f, sn = 0.f;
        #pragma unroll
        for (int s = 0; s < 4; ++s) {
            sr += red[s][fl][q];
            sz += red[s][fl][4 + q];
            sn += red[s][fl][8 + q];
        }
        const float rg = fast_sigmoid(gxr + sr + bhr);
        const float zg = fast_sigmoid(gxz + sz + bhz);
        const float ng = fast_tanh(gxn + rg * (sn + bhn));
        hreg = ng + zg * (hreg - ng);

        // ---- packed 4B agent-scope h store (lane pair shares one dword)
        unsigned int myu = (unsigned int)f2bf(hreg);
        unsigned int pu  = __shfl_xor(myu, 1);
        if (!(fl & 1))
            __hip_atomic_store((unsigned int*)(hbf + noff + (size_t)b * HID + j),
                               myu | (pu << 16),
                               __ATOMIC_RELAXED, __HIP_MEMORY_SCOPE_AGENT);

        // release: this wave's h stores ACKed at LLC, then block-wide barrier
        asm volatile("s_waitcnt vmcnt(0)" ::: "memory");
        bar_only();
        if (tid == 0)
            __hip_atomic_store(&flags[bg * 64 + jt], stamp,
                               __ATOMIC_RELAXED, __HIP_MEMORY_SCOPE_AGENT);

        // off the critical path: y store + next gx prefetch (finish under spin)
        y_all[(size_t)t * BH + (size_t)b * HID + j] = hreg;
        const int tsn = (ts + 1 < tc) ? ts + 1 : ts;
        const float* gxp = gx + (size_t)tsn * BATCH * G3;
        const float ngxr = gxp[(size_t)b * G3 + j];
        const float ngxz = gxp[(size_t)b * G3 + HID + j];
        const float ngxn = gxp[(size_t)b * G3 + 2 * HID + j];

        if (tid < 64) {    // wave 0 polls all 64 producer flags of this bg
            for (;;) {
                unsigned int f = __hip_atomic_load(&flags[bg * 64 + tid],
                                                   __ATOMIC_RELAXED,
                                                   __HIP_MEMORY_SCOPE_AGENT);
                if (__ballot(f >= stamp) == ~0ull) break;
                __builtin_amdgcn_s_sleep(1);
            }
        }
        bar_only();        // all 64 bg-blocks' h visible; guards red reuse
        gxr = ngxr; gxz = ngxz; gxn = ngxn;
    }
}

__global__ void copy_f32(const float* __restrict__ src, float* __restrict__ dst, int n)
{
    int i = blockIdx.x * blockDim.x + threadIdx.x;
    if (i < n) dst[i] = src[i];
}

// ---------------------------------------------------------------------------
extern "C" void kernel_launch(void* const* d_in, const int* in_sizes, int n_in,
                              void* d_out, int out_size, void* d_ws, size_t ws_size,
                              hipStream_t stream)
{
    const float* x    = (const float*)d_in[0];
    const float* h0   = (const float*)d_in[1];
    const float* wih[2] = {(const float*)d_in[2], (const float*)d_in[6]};
    const float* whh[2] = {(const float*)d_in[3], (const float*)d_in[7]};
    const float* bih[2] = {(const float*)d_in[4], (const float*)d_in[8]};
    const float* bhh[2] = {(const float*)d_in[5], (const float*)d_in[9]};

    float* out = (float*)d_out;
    float* y   = out;                                  // [512][64][1024]
    float* hn  = out + (size_t)T_STEPS * BH;           // [2][64][1024]

    const size_t WSZ = (size_t)G3 * HID;               // 3145728 elems
    unsigned short* wsu = (unsigned short*)d_ws;
    unsigned short* whh_bf[2] = {wsu, wsu + WSZ};
    unsigned short* wih_bf[2] = {wsu + 2 * WSZ, wsu + 3 * WSZ};
    unsigned short* hbf = wsu + 4 * WSZ;               // 2 x BH bf16 ping-pong
    unsigned int* flags = (unsigned int*)(wsu + 4 * WSZ + 2 * (size_t)BH);
    const size_t FLAG_N = 4 * 64;
    float* gx = (float*)((char*)flags + FLAG_N * sizeof(unsigned int));
    const size_t fixed_bytes = (4 * WSZ + 2 * (size_t)BH) * 2 + FLAG_N * 4;
    const size_t gx_bytes = ws_size > fixed_bytes ? ws_size - fixed_bytes : 0;

    int TC = 512;
    while (TC > 2 && (size_t)TC * BATCH * G3 * 4 > gx_bytes) TC >>= 1;

    hipMemsetAsync(flags, 0, FLAG_N * sizeof(unsigned int), stream);

    for (int layer = 0; layer < 2; ++layer) {
        cvt_f32_bf16<<<(int)(WSZ / 1024), 256, 0, stream>>>(whh[layer], whh_bf[layer], (int)WSZ);
        cvt_f32_bf16<<<(int)(WSZ / 1024), 256, 0, stream>>>(wih[layer], wih_bf[layer], (int)WSZ);
    }

    for (int layer = 0; layer < 2; ++layer) {
        const float* A_all = (layer == 0) ? x : y;
        const float* hinit = h0 + (size_t)layer * BH;

        cvt_f32_bf16<<<BH / 1024, 256, 0, stream>>>(hinit, hbf, BH);

        for (int c0 = 0; c0 < T_STEPS; c0 += TC) {
            dim3 ggrid(G3 / 128, TC * BATCH / 128);
            gemm_gx_bf16<<<ggrid, 256, 0, stream>>>(
                A_all + (size_t)c0 * BH, wih_bf[layer], bih[layer],
                gx, TC * BATCH);

            const float* gxp = gx;
            const float* hprev0 = (c0 == 0) ? hinit : (y + (size_t)(c0 - 1) * BH);
            const unsigned short* whhp = whh_bf[layer];
            const float* bhhp = bhh[layer];
            float* yp = y;
            unsigned short* hbfp = hbf;
            unsigned int* flp = flags;
            int sb = layer * T_STEPS + c0;
            int t0v = c0, tcv = TC;
            void* kargs[] = {(void*)&gxp, (void*)&hbfp, (void*)&hprev0,
                             (void*)&whhp, (void*)&bhhp, (void*)&yp,
                             (void*)&flp, (void*)&sb, (void*)&t0v, (void*)&tcv};
            hipLaunchCooperativeKernel((const void*)gru_persist,
                                       dim3(256), dim3(256), kargs, 0, stream);
        }
        copy_f32<<<(BH + 255) / 256, 256, 0, stream>>>(
            y + (size_t)(T_STEPS - 1) * BH, hn + (size_t)layer * BH, BH);
    }
}